// Round 2
// baseline (156.347 us; speedup 1.0000x reference)
//
#include <hip/hip_runtime.h>

// Problem constants (fixed by setup_inputs)
#define NB  8     // batch
#define SS  500   // seq
#define UU  128   // units (also GH*GD)
#define NG  5     // ngrams per chunk
#define CC  100   // chunks = S/NG
#define PP  10    // C(5,2) pairs
#define FF  20    // 2*PP edge-concat feature width
#define HH  5     // per-chunk heads
#define HD  10    // HH * DK (DK=2)
#define GHH 4     // graph heads
#define GDD 32    // graph head dim

// ---------------------------------------------------------------------------
// K1 v2: per-chunk edge MHA + leaky_relu + mean + pos -> g (d_out)
//        + fused graph qkv projection -> gq/gk/gv (workspace)
// block = (b,c), 640 threads: tid = h*128 + u  (h is wave-uniform)
// Each thread owns attention for ONE (u, head): 128-iter chain, not 640.
// ---------------------------------------------------------------------------
__global__ __launch_bounds__(640) void k1_chunk_mha(
    const float* __restrict__ x,   const float* __restrict__ wq,
    const float* __restrict__ bq,  const float* __restrict__ wk,
    const float* __restrict__ bk,  const float* __restrict__ wv,
    const float* __restrict__ bv,  const float* __restrict__ wo,
    const float* __restrict__ bo,  const float* __restrict__ pos,
    const float* __restrict__ gwq, const float* __restrict__ gbq,
    const float* __restrict__ gwk, const float* __restrict__ gbk,
    const float* __restrict__ gwv, const float* __restrict__ gbv,
    float* __restrict__ g_out, float* __restrict__ gq_out,
    float* __restrict__ gk_out, float* __restrict__ gv_out)
{
    const int bc = blockIdx.x;
    const int b  = bc / CC, c = bc % CC;
    const int u  = threadIdx.x & 127;
    const int h  = threadIdx.x >> 7;          // 0..4, uniform per wave

    __shared__ float4 s_kv[UU][HH];           // (k0,k1,v0,v1) per (u, head)
    __shared__ float2 s_o[UU][HH];            // attention outputs
    __shared__ float  s_part[HH][UU];         // leaky-mean partials
    __shared__ float  s_g[UU];                // g row for this (b,c)
    __shared__ float  s_red[3][HH][UU];       // graph qkv partials

    // ---- 5 ngram values for (b,c,u) -> 20 edge features (per-thread regs)
    float xv[NG];
    const float* xb = x + (size_t)b * SS * UU + (size_t)c * NG * UU + u;
#pragma unroll
    for (int t = 0; t < NG; ++t) xv[t] = xb[t * UU];    // coalesced across u

    const int II[PP] = {0,0,0,0,1,1,1,2,2,3};
    const int JJ[PP] = {1,2,3,4,2,3,4,3,4,4};
    float ht[FF];
#pragma unroll
    for (int p = 0; p < PP; ++p) { ht[2*p] = xv[II[p]]; ht[2*p+1] = xv[JJ[p]]; }

    // ---- qkv projection for head h only (weight idx wave-uniform -> s_load)
    const int cb = c * (FF * HD) + 2 * h;     // wq[c][f][h][d] flat
    float q0 = bq[c*HD + 2*h], q1 = bq[c*HD + 2*h + 1];
    float k0 = bk[c*HD + 2*h], k1 = bk[c*HD + 2*h + 1];
    float v0 = bv[c*HD + 2*h], v1 = bv[c*HD + 2*h + 1];
#pragma unroll
    for (int f = 0; f < FF; ++f) {
        const float hf = ht[f];
        q0 = fmaf(hf, wq[cb + f*HD],     q0);
        q1 = fmaf(hf, wq[cb + f*HD + 1], q1);
        k0 = fmaf(hf, wk[cb + f*HD],     k0);
        k1 = fmaf(hf, wk[cb + f*HD + 1], k1);
        v0 = fmaf(hf, wv[cb + f*HD],     v0);
        v1 = fmaf(hf, wv[cb + f*HD + 1], v1);
    }
    s_kv[u][h] = make_float4(k0, k1, v0, v1);
    __syncthreads();

    // ---- attention over v-axis (scores O(0.1): shift-free softmax is exact)
    const float scale = 0.7071067811865476f;  // 1/sqrt(dk=2)
    q0 *= scale; q1 *= scale;
    float l = 0.f, o0 = 0.f, o1 = 0.f;
#pragma unroll 4
    for (int vi = 0; vi < UU; ++vi) {
        const float4 kvv = s_kv[vi][h];       // ds_read_b128 broadcast
        const float s = fmaf(q0, kvv.x, q1 * kvv.y);
        const float e = __expf(s);
        l += e;
        o0 = fmaf(e, kvv.z, o0);
        o1 = fmaf(e, kvv.w, o1);
    }
    const float inv = 1.f / l;
    s_o[u][h] = make_float2(o0 * inv, o1 * inv);
    __syncthreads();

    // ---- output projection + residual + leaky(0.3), 4 f's per head-group
    float ov[HD];
#pragma unroll
    for (int h2 = 0; h2 < HH; ++h2) {
        const float2 t2 = s_o[u][h2];
        ov[2*h2] = t2.x; ov[2*h2+1] = t2.y;
    }
    const float* woc = wo + c * (HD * FF);
    float part = 0.f;
#pragma unroll
    for (int j = 0; j < 4; ++j) {
        const int f = h * 4 + j;              // wave-uniform
        float acc = bo[c*FF + f];
#pragma unroll
        for (int hd = 0; hd < HD; ++hd) acc = fmaf(ov[hd], woc[hd*FF + f], acc);
        const float a = ht[f] + acc;
        part += (a > 0.f) ? a : 0.3f * a;
    }
    s_part[h][u] = part;
    __syncthreads();

    if (h == 0) {
        const float gsum = s_part[0][u] + s_part[1][u] + s_part[2][u]
                         + s_part[3][u] + s_part[4][u];
        const float g = gsum * (1.f / FF) + pos[c*UU + u];
        s_g[u] = g;
        g_out[(size_t)bc*UU + u] = g;
    }
    __syncthreads();

    // ---- graph qkv projection, u2-range split across head-groups
    const int st = h * 26, en = (h == 4) ? UU : st + 26;   // wave-uniform
    float aq = (h == 0) ? gbq[u] : 0.f;
    float ak = (h == 0) ? gbk[u] : 0.f;
    float av = (h == 0) ? gbv[u] : 0.f;
    for (int u2 = st; u2 < en; ++u2) {
        const float gu = s_g[u2];             // LDS broadcast
        aq = fmaf(gu, gwq[u2*UU + u], aq);    // coalesced across u
        ak = fmaf(gu, gwk[u2*UU + u], ak);
        av = fmaf(gu, gwv[u2*UU + u], av);
    }
    s_red[0][h][u] = aq; s_red[1][h][u] = ak; s_red[2][h][u] = av;
    __syncthreads();

    if (h < 3) {                               // wave-uniform branch
        const float sum = s_red[h][0][u] + s_red[h][1][u] + s_red[h][2][u]
                        + s_red[h][3][u] + s_red[h][4][u];
        if (h == 0)      gq_out[(size_t)bc*UU + u] = sum * 0.17677669529663687f;
        else if (h == 1) gk_out[(size_t)bc*UU + u] = sum;
        else             gv_out[(size_t)bc*UU + u] = sum;
    }
}

// ---------------------------------------------------------------------------
// K2 v2 (fused graph attention + output projection + residual)
// block = (b,q) -> 800 blocks, 128 threads.
//   phase 1: thread = k (t<100): all 4 head scores, exp -> s_e
//   phase 2: thread = (h,d): o, l accumulated over k (l redundant per thread)
//   phase 3: thread = u: out = g + sum_hd o[hd]*gwo[hd,u] + gbo[u]
// ---------------------------------------------------------------------------
__global__ __launch_bounds__(128) void k2_graph(
    const float* __restrict__ gq, const float* __restrict__ gk,
    const float* __restrict__ gv, const float* __restrict__ gwo,
    const float* __restrict__ gbo, float* __restrict__ out)
{
    const int bq = blockIdx.x;
    const int b  = bq / CC;
    const int t  = threadIdx.x;

    __shared__ float s_q[UU];
    __shared__ float s_e[GHH][CC];
    __shared__ float s_o[UU];

    const float gval = out[(size_t)bq*UU + t];     // g (written by K1)
    s_q[t] = gq[(size_t)bq*UU + t];                // already scaled
    __syncthreads();

    // phase 1: scores + exp for row k = t
    if (t < CC) {
        const float4* krow = (const float4*)(gk + ((size_t)b*CC + t)*UU);
        const float4* q4   = (const float4*)s_q;   // uniform addr -> broadcast
#pragma unroll
        for (int hh = 0; hh < GHH; ++hh) {
            float s = 0.f;
#pragma unroll
            for (int i = 0; i < 8; ++i) {
                const float4 kf = krow[hh*8 + i];
                const float4 qf = q4[hh*8 + i];
                s = fmaf(qf.x, kf.x, s); s = fmaf(qf.y, kf.y, s);
                s = fmaf(qf.z, kf.z, s); s = fmaf(qf.w, kf.w, s);
            }
            s_e[hh][t] = __expf(s);                // scores tiny: shift-free
        }
    }
    __syncthreads();

    // phase 2: o[t], l for head h = t>>5 (l redundant per thread: no reduce)
    {
        const int h = t >> 5;
        const float* vcol = gv + (size_t)b*CC*UU + t;
        float l = 0.f, o = 0.f;
#pragma unroll 4
        for (int k = 0; k < CC; ++k) {
            const float e = s_e[h][k];             // 2 addrs/wave: free
            l += e;
            o = fmaf(e, vcol[(size_t)k*UU], o);    // coalesced across t
        }
        s_o[t] = o / l;
    }
    __syncthreads();

    // phase 3: output matvec + residual
    float acc = gbo[t];
#pragma unroll 4
    for (int hd = 0; hd < UU; ++hd)
        acc = fmaf(s_o[hd], gwo[hd*UU + t], acc);  // gwo coalesced across t
    out[(size_t)bq*UU + t] = gval + acc;
}

extern "C" void kernel_launch(void* const* d_in, const int* in_sizes, int n_in,
                              void* d_out, int out_size, void* d_ws, size_t ws_size,
                              hipStream_t stream)
{
    (void)in_sizes; (void)n_in; (void)out_size; (void)ws_size;
    const float* x   = (const float*)d_in[0];
    const float* wq  = (const float*)d_in[1];
    const float* bq  = (const float*)d_in[2];
    const float* wk  = (const float*)d_in[3];
    const float* bk  = (const float*)d_in[4];
    const float* wv  = (const float*)d_in[5];
    const float* bv  = (const float*)d_in[6];
    const float* wo  = (const float*)d_in[7];
    const float* bo  = (const float*)d_in[8];
    const float* pos = (const float*)d_in[9];
    const float* gwq = (const float*)d_in[10];
    const float* gbq = (const float*)d_in[11];
    const float* gwk = (const float*)d_in[12];
    const float* gbk = (const float*)d_in[13];
    const float* gwv = (const float*)d_in[14];
    const float* gbv = (const float*)d_in[15];
    const float* gwo = (const float*)d_in[16];
    const float* gbo = (const float*)d_in[17];
    float* out = (float*)d_out;
    float* ws  = (float*)d_ws;

    float* gq_ws = ws;              // [8*100*128]
    float* gk_ws = ws + 102400;
    float* gv_ws = ws + 204800;

    k1_chunk_mha<<<NB*CC, 640, 0, stream>>>(x, wq, bq, wk, bk, wv, bv, wo, bo,
        pos, gwq, gbq, gwk, gbk, gwv, gbv, out, gq_ws, gk_ws, gv_ws);
    k2_graph<<<NB*CC, 128, 0, stream>>>(gq_ws, gk_ws, gv_ws, gwo, gbo, out);
}